// Round 1
// baseline (1334.744 us; speedup 1.0000x reference)
//
#include <hip/hip_runtime.h>

// Problem constants (fixed by the reference)
#define NHEADS 8
#define NKVH   2
#define HD     256
#define SEQ    4096
#define HID    2048
#define QKVN   3072   // (NH + 2*NKV) * D
#define SCAL   (1.0f/256.0f)

typedef __attribute__((ext_vector_type(8))) __bf16 bf16x8;
typedef __attribute__((ext_vector_type(4))) float  f32x4;

__device__ __forceinline__ unsigned short f2bf(float f) {
  unsigned int u = __builtin_bit_cast(unsigned int, f);
  u += 0x7fffu + ((u >> 16) & 1u);          // round-to-nearest-even
  return (unsigned short)(u >> 16);
}
__device__ __forceinline__ float bf2f(unsigned short b) {
  return __builtin_bit_cast(float, (unsigned int)b << 16);
}

// async global->LDS, 16B per lane (linear LDS dest = wave base + lane*16)
__device__ __forceinline__ void async_copy16(const void* g, void* l) {
  __builtin_amdgcn_global_load_lds(
      (__attribute__((address_space(1))) void*)(g),
      (__attribute__((address_space(3))) void*)(l), 16, 0, 0);
}

// ---------------------------------------------------------------- fp32->bf16
__global__ __launch_bounds__(256) void cvt_bf16(const float* __restrict__ in,
                                                unsigned short* __restrict__ out,
                                                int n4) {
  int i = blockIdx.x * 256 + threadIdx.x;
  if (i >= n4) return;
  float4 v = reinterpret_cast<const float4*>(in)[i];
  ushort4 o;
  o.x = f2bf(v.x); o.y = f2bf(v.y); o.z = f2bf(v.z); o.w = f2bf(v.w);
  reinterpret_cast<ushort4*>(out)[i] = o;
}

// ------------------------------------------------------- C = A(M,K) * B(N,K)^T
// 128x128 tile, BK=64, 4 waves as 2x2 of 64x64. LDS chunk layout with XOR
// swizzle: chunk(kc,row,slot) = kc*512 + row*4 + slot, data(slot) = global
// j8 = slot ^ (row&3).  Read side uses slot = (lane>>4) ^ (row&3).
template <bool OUT_BF16>
__global__ __launch_bounds__(256) void gemm_bt(const unsigned short* __restrict__ A,
                                               const unsigned short* __restrict__ B,
                                               void* __restrict__ C,
                                               int M, int N, int K) {
  __shared__ __align__(16) unsigned short Als[128 * 64];
  __shared__ __align__(16) unsigned short Bls[128 * 64];
  const int t    = threadIdx.x;
  const int lane = t & 63;
  const int wid  = t >> 6;
  const int wr = wid >> 1, wc = wid & 1;
  const int l15 = lane & 15, lg = lane >> 4;
  const int m0 = blockIdx.y * 128, n0 = blockIdx.x * 128;

  f32x4 acc[4][4] = {};

  for (int k0 = 0; k0 < K; k0 += 64) {
    __syncthreads();                                  // LDS reuse fence
#pragma unroll
    for (int i = 0; i < 4; ++i) {
      int c   = i * 256 + t;                          // 16B chunk index 0..1023
      int kc  = c >> 9;
      int row = (c >> 2) & 127;
      int j8  = (c & 3) ^ (row & 3);                  // inverse-swizzled source
      int gcol = k0 + kc * 32 + j8 * 8;
      async_copy16(A + (size_t)(m0 + row) * K + gcol, Als + c * 8);
      async_copy16(B + (size_t)(n0 + row) * K + gcol, Bls + c * 8);
    }
    __syncthreads();                                  // drains vmcnt before use
#pragma unroll
    for (int kc = 0; kc < 2; ++kc) {
      bf16x8 af[4], bfr[4];
#pragma unroll
      for (int m = 0; m < 4; ++m) {
        int row   = wr * 64 + m * 16 + l15;
        int chunk = kc * 512 + row * 4 + (lg ^ (row & 3));
        af[m] = *reinterpret_cast<const bf16x8*>(Als + chunk * 8);
      }
#pragma unroll
      for (int n = 0; n < 4; ++n) {
        int row   = wc * 64 + n * 16 + l15;
        int chunk = kc * 512 + row * 4 + (lg ^ (row & 3));
        bfr[n] = *reinterpret_cast<const bf16x8*>(Bls + chunk * 8);
      }
#pragma unroll
      for (int m = 0; m < 4; ++m)
#pragma unroll
        for (int n = 0; n < 4; ++n)
          acc[m][n] = __builtin_amdgcn_mfma_f32_16x16x32_bf16(af[m], bfr[n],
                                                              acc[m][n], 0, 0, 0);
    }
  }

#pragma unroll
  for (int m = 0; m < 4; ++m) {
#pragma unroll
    for (int n = 0; n < 4; ++n) {
      int col = n0 + wc * 64 + n * 16 + l15;
#pragma unroll
      for (int r = 0; r < 4; ++r) {
        int rowg = m0 + wr * 64 + m * 16 + lg * 4 + r;   // C/D: row=(l>>4)*4+r
        if constexpr (OUT_BF16)
          reinterpret_cast<unsigned short*>(C)[(size_t)rowg * N + col] =
              f2bf(acc[m][n][r]);
        else
          reinterpret_cast<float*>(C)[(size_t)rowg * N + col] = acc[m][n][r];
      }
    }
  }
}

// --------------------------------------------- RMSNorm + RoPE + layout split
// one wave per (s, comp) row of 256 elems; comp 0..7 = q heads, 8..9 = k,
// 10..11 = v.  q gets *SCAL folded in; v is written transposed (d-major).
__global__ __launch_bounds__(256) void postproc(const unsigned short* __restrict__ qkv,
                                                const float* __restrict__ cosb,
                                                const float* __restrict__ sinb,
                                                unsigned short* __restrict__ q,
                                                unsigned short* __restrict__ k,
                                                unsigned short* __restrict__ vt) {
  const int wid = threadIdx.x >> 6, lane = threadIdx.x & 63;
  const int task = blockIdx.x * 4 + wid;          // 0 .. SEQ*12-1
  const int s = task / 12, comp = task % 12;

  ushort4 raw = reinterpret_cast<const ushort4*>(qkv + (size_t)task * 256)[lane];
  float x0 = bf2f(raw.x), x1 = bf2f(raw.y), x2 = bf2f(raw.z), x3 = bf2f(raw.w);

  float ss = x0 * x0 + x1 * x1 + x2 * x2 + x3 * x3;
#pragma unroll
  for (int m = 1; m < 64; m <<= 1) ss += __shfl_xor(ss, m);
  float inv = rsqrtf(ss * (1.0f / 256.0f) + 1e-6f);
  x0 *= inv; x1 *= inv; x2 *= inv; x3 *= inv;

  if (comp < 10) {  // RoPE for q,k: lane d-range 4*lane..4*lane+3, partner ±128
    float4 c  = reinterpret_cast<const float4*>(cosb + (size_t)s * 256)[lane];
    float4 sn = reinterpret_cast<const float4*>(sinb + (size_t)s * 256)[lane];
    float p0 = __shfl_xor(x0, 32), p1 = __shfl_xor(x1, 32);
    float p2 = __shfl_xor(x2, 32), p3 = __shfl_xor(x3, 32);
    float sg = (lane < 32) ? -1.0f : 1.0f;       // rotate_half sign
    x0 = x0 * c.x + sg * p0 * sn.x;
    x1 = x1 * c.y + sg * p1 * sn.y;
    x2 = x2 * c.z + sg * p2 * sn.z;
    x3 = x3 * c.w + sg * p3 * sn.w;
  }

  if (comp < 8) {
    ushort4 o;
    o.x = f2bf(x0 * SCAL); o.y = f2bf(x1 * SCAL);
    o.z = f2bf(x2 * SCAL); o.w = f2bf(x3 * SCAL);
    reinterpret_cast<ushort4*>(q + ((size_t)s * NHEADS + comp) * 256)[lane] = o;
  } else if (comp < 10) {
    ushort4 o;
    o.x = f2bf(x0); o.y = f2bf(x1); o.z = f2bf(x2); o.w = f2bf(x3);
    reinterpret_cast<ushort4*>(k + ((size_t)(comp - 8) * SEQ + s) * 256)[lane] = o;
  } else {  // v -> V^T[kvh][d][s]
    size_t base = (size_t)(comp - 10) * 256 * SEQ + s;
    int d0 = lane * 4;
    vt[base + (size_t)(d0 + 0) * SEQ] = f2bf(x0);
    vt[base + (size_t)(d0 + 1) * SEQ] = f2bf(x1);
    vt[base + (size_t)(d0 + 2) * SEQ] = f2bf(x2);
    vt[base + (size_t)(d0 + 3) * SEQ] = f2bf(x3);
  }
}

// --------------------------------------------------- causal flash attention
// grid (SEQ/64, NH); 4 waves/block, each wave owns 16 q-rows, KV tile = 64.
// Q scaled by 1/256 already.  K (kvh,S,D) row-major; V^T (kvh,D,S).
__global__ __launch_bounds__(256) void flash(const unsigned short* __restrict__ q,
                                             const unsigned short* __restrict__ k,
                                             const unsigned short* __restrict__ vt,
                                             unsigned short* __restrict__ attn) {
  __shared__ __align__(16) unsigned short P[4][16][72];   // per-wave, pad 8
  const int lane = threadIdx.x & 63, wid = threadIdx.x >> 6;
  const int l15 = lane & 15, lg = lane >> 4;
  const int h = blockIdx.y, kvh = h >> 2;                 // rep = NH/NKV = 4
  const int qt = gridDim.x - 1 - blockIdx.x;              // biggest tiles first
  const int qb = qt * 64 + wid * 16;

  bf16x8 qf[8];
  {
    const unsigned short* qrow = q + ((size_t)(qb + l15) * NHEADS + h) * 256 + lg * 8;
#pragma unroll
    for (int kc = 0; kc < 8; ++kc)
      qf[kc] = *reinterpret_cast<const bf16x8*>(qrow + kc * 32);
  }

  f32x4 o[16];
#pragma unroll
  for (int i = 0; i < 16; ++i) o[i] = f32x4{0.f, 0.f, 0.f, 0.f};
  float mrow[4] = {-1e30f, -1e30f, -1e30f, -1e30f};
  float lrow[4] = {0.f, 0.f, 0.f, 0.f};

  const unsigned short* kbase = k + (size_t)kvh * SEQ * 256;
  const unsigned short* vbase = vt + (size_t)kvh * 256 * SEQ + (size_t)l15 * SEQ + lg * 8;

  const int ntiles = qt + 1;
  for (int tkv = 0; tkv < ntiles; ++tkv) {
    const int kvb = tkv * 64;

    f32x4 sacc[4];
#pragma unroll
    for (int n = 0; n < 4; ++n) {
      f32x4 a = f32x4{0.f, 0.f, 0.f, 0.f};
      const unsigned short* krow = kbase + (size_t)(kvb + n * 16 + l15) * 256 + lg * 8;
#pragma unroll
      for (int kc = 0; kc < 8; ++kc) {
        bf16x8 bfr = *reinterpret_cast<const bf16x8*>(krow + kc * 32);
        a = __builtin_amdgcn_mfma_f32_16x16x32_bf16(qf[kc], bfr, a, 0, 0, 0);
      }
      sacc[n] = a;
    }

    if (kvb + 64 > qb + 1) {  // boundary tile: apply causal mask
#pragma unroll
      for (int n = 0; n < 4; ++n) {
        int col = kvb + n * 16 + l15;
#pragma unroll
        for (int r = 0; r < 4; ++r)
          if (col > qb + lg * 4 + r) sacc[n][r] = -1e30f;
      }
    }

    float scal[4];
#pragma unroll
    for (int r = 0; r < 4; ++r) {
      float tm = fmaxf(fmaxf(sacc[0][r], sacc[1][r]), fmaxf(sacc[2][r], sacc[3][r]));
      tm = fmaxf(tm, __shfl_xor(tm, 1));
      tm = fmaxf(tm, __shfl_xor(tm, 2));
      tm = fmaxf(tm, __shfl_xor(tm, 4));
      tm = fmaxf(tm, __shfl_xor(tm, 8));
      float mnew = fmaxf(mrow[r], tm);
      scal[r] = __expf(mrow[r] - mnew);
      mrow[r] = mnew;
      float rs = 0.f;
#pragma unroll
      for (int n = 0; n < 4; ++n) {
        float p = __expf(sacc[n][r] - mnew);
        sacc[n][r] = p;
        rs += p;
      }
      rs += __shfl_xor(rs, 1);
      rs += __shfl_xor(rs, 2);
      rs += __shfl_xor(rs, 4);
      rs += __shfl_xor(rs, 8);
      lrow[r] = lrow[r] * scal[r] + rs;
    }

    // P (C/D layout) -> LDS row-major, then re-read as A-frags
#pragma unroll
    for (int n = 0; n < 4; ++n)
#pragma unroll
      for (int r = 0; r < 4; ++r)
        P[wid][lg * 4 + r][n * 16 + l15] = f2bf(sacc[n][r]);

#pragma unroll
    for (int i = 0; i < 16; ++i)
#pragma unroll
      for (int r = 0; r < 4; ++r) o[i][r] *= scal[r];

    asm volatile("s_waitcnt lgkmcnt(0)" ::: "memory");  // cross-lane LDS visibility

#pragma unroll
    for (int kvc = 0; kvc < 2; ++kvc) {
      bf16x8 pa = *reinterpret_cast<const bf16x8*>(&P[wid][l15][kvc * 32 + lg * 8]);
      const unsigned short* vrow = vbase + kvb + kvc * 32;
#pragma unroll
      for (int dt = 0; dt < 16; ++dt) {
        bf16x8 vf = *reinterpret_cast<const bf16x8*>(vrow + (size_t)dt * 16 * SEQ);
        o[dt] = __builtin_amdgcn_mfma_f32_16x16x32_bf16(pa, vf, o[dt], 0, 0, 0);
      }
    }
  }

#pragma unroll
  for (int dt = 0; dt < 16; ++dt)
#pragma unroll
    for (int r = 0; r < 4; ++r) {
      float v = o[dt][r] / lrow[r];
      attn[(size_t)(qb + lg * 4 + r) * HID + h * 256 + dt * 16 + l15] = f2bf(v);
    }
}

// ---------------------------------------------------------------- launcher
extern "C" void kernel_launch(void* const* d_in, const int* in_sizes, int n_in,
                              void* d_out, int out_size, void* d_ws, size_t ws_size,
                              hipStream_t stream) {
  const float* hs   = (const float*)d_in[0];
  const float* cosb = (const float*)d_in[1];
  const float* sinb = (const float*)d_in[2];
  const float* qkvw = (const float*)d_in[3];
  const float* ow   = (const float*)d_in[4];

  char* ws = (char*)d_ws;
  // byte offsets (total 88,080,384 B)
  unsigned short* hs_bf   = (unsigned short*)(ws + 0);           // 16 MB
  unsigned short* wqkv_bf = (unsigned short*)(ws + 16777216);    // 12 MB
  unsigned short* wo_bf   = (unsigned short*)(ws + 29360128);    //  8 MB
  unsigned short* qkv_bf  = (unsigned short*)(ws + 37748736);    // 24 MB
  unsigned short* attn_bf = qkv_bf;                              // reuse (dead after postproc)
  unsigned short* q_bf    = (unsigned short*)(ws + 62914560);    // 16 MB
  unsigned short* k_bf    = (unsigned short*)(ws + 79691776);    //  4 MB
  unsigned short* vt_bf   = (unsigned short*)(ws + 83886080);    //  4 MB

  cvt_bf16<<<dim3((SEQ * HID / 4 + 255) / 256), dim3(256), 0, stream>>>(hs, hs_bf, SEQ * HID / 4);
  cvt_bf16<<<dim3((QKVN * HID / 4 + 255) / 256), dim3(256), 0, stream>>>(qkvw, wqkv_bf, QKVN * HID / 4);
  cvt_bf16<<<dim3((HID * HID / 4 + 255) / 256), dim3(256), 0, stream>>>(ow, wo_bf, HID * HID / 4);

  gemm_bt<true><<<dim3(QKVN / 128, SEQ / 128), dim3(256), 0, stream>>>(
      hs_bf, wqkv_bf, qkv_bf, SEQ, QKVN, HID);

  postproc<<<dim3(SEQ * 12 / 4), dim3(256), 0, stream>>>(qkv_bf, cosb, sinb, q_bf, k_bf, vt_bf);

  flash<<<dim3(SEQ / 64, NHEADS), dim3(256), 0, stream>>>(q_bf, k_bf, vt_bf, attn_bf);

  gemm_bt<false><<<dim3(HID / 128, SEQ / 128), dim3(256), 0, stream>>>(
      attn_bf, wo_bf, d_out, SEQ, HID, HID);
}

// Round 2
// 858.306 us; speedup vs baseline: 1.5551x; 1.5551x over previous
//
#include <hip/hip_runtime.h>

// Problem constants (fixed by the reference)
#define NHEADS 8
#define NKVH   2
#define HD     256
#define SEQ    4096
#define HID    2048
#define QKVN   3072   // (NH + 2*NKV) * D
#define SCAL   (1.0f/256.0f)

typedef __attribute__((ext_vector_type(8))) __bf16 bf16x8;
typedef __attribute__((ext_vector_type(4))) float  f32x4;

__device__ __forceinline__ unsigned short f2bf(float f) {
  unsigned int u = __builtin_bit_cast(unsigned int, f);
  u += 0x7fffu + ((u >> 16) & 1u);          // round-to-nearest-even
  return (unsigned short)(u >> 16);
}
__device__ __forceinline__ float bf2f(unsigned short b) {
  return __builtin_bit_cast(float, (unsigned int)b << 16);
}

// async global->LDS, 16B per lane (linear LDS dest = wave base + lane*16)
__device__ __forceinline__ void async_copy16(const void* g, void* l) {
  __builtin_amdgcn_global_load_lds(
      (__attribute__((address_space(1))) void*)(g),
      (__attribute__((address_space(3))) void*)(l), 16, 0, 0);
}

// ---------------------------------------------------------------- fp32->bf16
__global__ __launch_bounds__(256) void cvt_bf16(const float* __restrict__ in,
                                                unsigned short* __restrict__ out,
                                                int n4) {
  int i = blockIdx.x * 256 + threadIdx.x;
  if (i >= n4) return;
  float4 v = reinterpret_cast<const float4*>(in)[i];
  ushort4 o;
  o.x = f2bf(v.x); o.y = f2bf(v.y); o.z = f2bf(v.z); o.w = f2bf(v.w);
  reinterpret_cast<ushort4*>(out)[i] = o;
}

// ------------------------------------------------------- C = A(M,K) * B(N,K)^T
// 128x128 tile, BK=64, 4 waves as 2x2 of 64x64. LDS chunk layout with XOR
// swizzle: chunk(kc,row,slot) = kc*512 + row*4 + slot, data(slot) = global
// j8 = slot ^ (row&3).  Read side uses slot = (lane>>4) ^ (row&3).
template <bool OUT_BF16>
__global__ __launch_bounds__(256) void gemm_bt(const unsigned short* __restrict__ A,
                                               const unsigned short* __restrict__ B,
                                               void* __restrict__ C,
                                               int M, int N, int K) {
  __shared__ __align__(16) unsigned short Als[128 * 64];
  __shared__ __align__(16) unsigned short Bls[128 * 64];
  const int t    = threadIdx.x;
  const int lane = t & 63;
  const int wid  = t >> 6;
  const int wr = wid >> 1, wc = wid & 1;
  const int l15 = lane & 15, lg = lane >> 4;
  const int m0 = blockIdx.y * 128, n0 = blockIdx.x * 128;

  f32x4 acc[4][4] = {};

  for (int k0 = 0; k0 < K; k0 += 64) {
    __syncthreads();                                  // LDS reuse fence
#pragma unroll
    for (int i = 0; i < 4; ++i) {
      int c   = i * 256 + t;                          // 16B chunk index 0..1023
      int kc  = c >> 9;
      int row = (c >> 2) & 127;
      int j8  = (c & 3) ^ (row & 3);                  // inverse-swizzled source
      int gcol = k0 + kc * 32 + j8 * 8;
      async_copy16(A + (size_t)(m0 + row) * K + gcol, Als + c * 8);
      async_copy16(B + (size_t)(n0 + row) * K + gcol, Bls + c * 8);
    }
    __syncthreads();                                  // drains vmcnt before use
#pragma unroll
    for (int kc = 0; kc < 2; ++kc) {
      bf16x8 af[4], bfr[4];
#pragma unroll
      for (int m = 0; m < 4; ++m) {
        int row   = wr * 64 + m * 16 + l15;
        int chunk = kc * 512 + row * 4 + (lg ^ (row & 3));
        af[m] = *reinterpret_cast<const bf16x8*>(Als + chunk * 8);
      }
#pragma unroll
      for (int n = 0; n < 4; ++n) {
        int row   = wc * 64 + n * 16 + l15;
        int chunk = kc * 512 + row * 4 + (lg ^ (row & 3));
        bfr[n] = *reinterpret_cast<const bf16x8*>(Bls + chunk * 8);
      }
#pragma unroll
      for (int m = 0; m < 4; ++m)
#pragma unroll
        for (int n = 0; n < 4; ++n)
          acc[m][n] = __builtin_amdgcn_mfma_f32_16x16x32_bf16(af[m], bfr[n],
                                                              acc[m][n], 0, 0, 0);
    }
  }

#pragma unroll
  for (int m = 0; m < 4; ++m) {
#pragma unroll
    for (int n = 0; n < 4; ++n) {
      int col = n0 + wc * 64 + n * 16 + l15;
#pragma unroll
      for (int r = 0; r < 4; ++r) {
        int rowg = m0 + wr * 64 + m * 16 + lg * 4 + r;   // C/D: row=(l>>4)*4+r
        if constexpr (OUT_BF16)
          reinterpret_cast<unsigned short*>(C)[(size_t)rowg * N + col] =
              f2bf(acc[m][n][r]);
        else
          reinterpret_cast<float*>(C)[(size_t)rowg * N + col] = acc[m][n][r];
      }
    }
  }
}

// --------------------------------------------- RMSNorm + RoPE + layout split
__global__ __launch_bounds__(256) void postproc(const unsigned short* __restrict__ qkv,
                                                const float* __restrict__ cosb,
                                                const float* __restrict__ sinb,
                                                unsigned short* __restrict__ q,
                                                unsigned short* __restrict__ k,
                                                unsigned short* __restrict__ vt) {
  const int wid = threadIdx.x >> 6, lane = threadIdx.x & 63;
  const int task = blockIdx.x * 4 + wid;          // 0 .. SEQ*12-1
  const int s = task / 12, comp = task % 12;

  ushort4 raw = reinterpret_cast<const ushort4*>(qkv + (size_t)task * 256)[lane];
  float x0 = bf2f(raw.x), x1 = bf2f(raw.y), x2 = bf2f(raw.z), x3 = bf2f(raw.w);

  float ss = x0 * x0 + x1 * x1 + x2 * x2 + x3 * x3;
#pragma unroll
  for (int m = 1; m < 64; m <<= 1) ss += __shfl_xor(ss, m);
  float inv = rsqrtf(ss * (1.0f / 256.0f) + 1e-6f);
  x0 *= inv; x1 *= inv; x2 *= inv; x3 *= inv;

  if (comp < 10) {  // RoPE: lane d-range 4*lane..4*lane+3, partner ±128
    float4 c  = reinterpret_cast<const float4*>(cosb + (size_t)s * 256)[lane];
    float4 sn = reinterpret_cast<const float4*>(sinb + (size_t)s * 256)[lane];
    float p0 = __shfl_xor(x0, 32), p1 = __shfl_xor(x1, 32);
    float p2 = __shfl_xor(x2, 32), p3 = __shfl_xor(x3, 32);
    float sg = (lane < 32) ? -1.0f : 1.0f;       // rotate_half sign
    x0 = x0 * c.x + sg * p0 * sn.x;
    x1 = x1 * c.y + sg * p1 * sn.y;
    x2 = x2 * c.z + sg * p2 * sn.z;
    x3 = x3 * c.w + sg * p3 * sn.w;
  }

  if (comp < 8) {
    ushort4 o;
    o.x = f2bf(x0 * SCAL); o.y = f2bf(x1 * SCAL);
    o.z = f2bf(x2 * SCAL); o.w = f2bf(x3 * SCAL);
    reinterpret_cast<ushort4*>(q + ((size_t)s * NHEADS + comp) * 256)[lane] = o;
  } else if (comp < 10) {
    ushort4 o;
    o.x = f2bf(x0); o.y = f2bf(x1); o.z = f2bf(x2); o.w = f2bf(x3);
    reinterpret_cast<ushort4*>(k + ((size_t)(comp - 8) * SEQ + s) * 256)[lane] = o;
  } else {  // v -> V^T[kvh][d][s]
    size_t base = (size_t)(comp - 10) * 256 * SEQ + s;
    int d0 = lane * 4;
    vt[base + (size_t)(d0 + 0) * SEQ] = f2bf(x0);
    vt[base + (size_t)(d0 + 1) * SEQ] = f2bf(x1);
    vt[base + (size_t)(d0 + 2) * SEQ] = f2bf(x2);
    vt[base + (size_t)(d0 + 3) * SEQ] = f2bf(x3);
  }
}

// --------------------------------------------------- causal flash attention
// 512 blocks (1-D), 4 waves x 16 q-rows = 64 q-rows/block, KV tile = 64.
// K tile staged in LDS (double-buffered, global_load_lds w=16, 8-chunk XOR
// swizzle); V read from global V^T.  Block->(qt,h) map pairs heavy+light
// blocks (bid and bid+256 have complementary qt) for LPT-style balance.
__global__ __launch_bounds__(256) void flash(const unsigned short* __restrict__ q,
                                             const unsigned short* __restrict__ k,
                                             const unsigned short* __restrict__ vt,
                                             unsigned short* __restrict__ attn) {
  __shared__ __align__(16) unsigned short Kls[2][64 * 256];   // 2 x 32 KB
  __shared__ __align__(16) unsigned short P[4][16][72];       // per-wave, pad 8
  const int lane = threadIdx.x & 63, wid = threadIdx.x >> 6;
  const int l15 = lane & 15, lg = lane >> 4;

  const int bid = blockIdx.x;
  int qt, h;
  if (bid < 256) { qt = 63 - (bid >> 2); h = bid & 3; }
  else           { qt = (bid - 256) >> 2; h = 4 + ((bid - 256) & 3); }
  const int kvh = h >> 2;                                     // rep = 4
  const int qb = qt * 64 + wid * 16;

  bf16x8 qf[8];
  {
    const unsigned short* qrow = q + ((size_t)(qb + l15) * NHEADS + h) * 256 + lg * 8;
#pragma unroll
    for (int kc = 0; kc < 8; ++kc)
      qf[kc] = *reinterpret_cast<const bf16x8*>(qrow + kc * 32);
  }

  f32x4 o[16];
#pragma unroll
  for (int i = 0; i < 16; ++i) o[i] = f32x4{0.f, 0.f, 0.f, 0.f};
  float mrow[4] = {-1e30f, -1e30f, -1e30f, -1e30f};
  float lrow[4] = {0.f, 0.f, 0.f, 0.f};

  const unsigned short* kbase = k + (size_t)kvh * SEQ * 256;
  const unsigned short* vbase = vt + (size_t)kvh * 256 * SEQ + (size_t)l15 * SEQ + lg * 8;

  // stage one 64x256 K tile into Kls[b]: 2048 16B chunks, 8 per thread.
  // LDS chunk p (row=p>>5, pj=p&31) holds data chunk j=(pj&~7)|((pj^row)&7)
  // (involution; read side applies the same XOR).
  auto stage = [&](int b, int tkv) {
    const unsigned short* src = kbase + (size_t)tkv * 64 * 256;
#pragma unroll
    for (int qq = 0; qq < 8; ++qq) {
      int p   = (qq * 4 + wid) * 64 + lane;
      int row = p >> 5, pj = p & 31;
      int j   = (pj & ~7) | ((pj ^ row) & 7);
      async_copy16(src + row * 256 + j * 8, Kls[b] + p * 8);
    }
  };

  const int ntiles = qt + 1;
  int cur = 0;
  stage(0, 0);
  __syncthreads();                                   // drains vmcnt(0) too

  for (int tkv = 0; tkv < ntiles; ++tkv) {
    const int kvb = tkv * 64;
    if (tkv + 1 < ntiles) stage(cur ^ 1, tkv + 1);   // prefetch next tile

    // ---- QK^T from LDS (swizzled ds_read_b128, 2-way = free)
    f32x4 sacc[4];
    __builtin_amdgcn_s_setprio(1);
#pragma unroll
    for (int n = 0; n < 4; ++n) {
      f32x4 a = f32x4{0.f, 0.f, 0.f, 0.f};
      const int row = n * 16 + l15;
      const unsigned short* kr = Kls[cur] + row * 256;
#pragma unroll
      for (int kc = 0; kc < 8; ++kc) {
        int j  = kc * 4 + lg;
        int pj = (j & ~7) | ((j ^ row) & 7);
        bf16x8 bfr = *reinterpret_cast<const bf16x8*>(kr + pj * 8);
        a = __builtin_amdgcn_mfma_f32_16x16x32_bf16(qf[kc], bfr, a, 0, 0, 0);
      }
      sacc[n] = a;
    }
    __builtin_amdgcn_s_setprio(0);

    if (kvb + 64 > qb + 1) {  // boundary tile: causal mask
#pragma unroll
      for (int n = 0; n < 4; ++n) {
        int col = kvb + n * 16 + l15;
#pragma unroll
        for (int r = 0; r < 4; ++r)
          if (col > qb + lg * 4 + r) sacc[n][r] = -1e30f;
      }
    }

    // ---- online softmax (wave-parallel, 16-lane xor reduce per row group)
    float scal[4];
#pragma unroll
    for (int r = 0; r < 4; ++r) {
      float tm = fmaxf(fmaxf(sacc[0][r], sacc[1][r]), fmaxf(sacc[2][r], sacc[3][r]));
      tm = fmaxf(tm, __shfl_xor(tm, 1));
      tm = fmaxf(tm, __shfl_xor(tm, 2));
      tm = fmaxf(tm, __shfl_xor(tm, 4));
      tm = fmaxf(tm, __shfl_xor(tm, 8));
      float mnew = fmaxf(mrow[r], tm);
      scal[r] = __expf(mrow[r] - mnew);
      mrow[r] = mnew;
      float rs = 0.f;
#pragma unroll
      for (int n = 0; n < 4; ++n) {
        float p = __expf(sacc[n][r] - mnew);
        sacc[n][r] = p;
        rs += p;
      }
      rs += __shfl_xor(rs, 1);
      rs += __shfl_xor(rs, 2);
      rs += __shfl_xor(rs, 4);
      rs += __shfl_xor(rs, 8);
      lrow[r] = lrow[r] * scal[r] + rs;
    }

    // P (C/D layout) -> per-wave LDS, re-read as A-frags
#pragma unroll
    for (int n = 0; n < 4; ++n)
#pragma unroll
      for (int r = 0; r < 4; ++r)
        P[wid][lg * 4 + r][n * 16 + l15] = f2bf(sacc[n][r]);

#pragma unroll
    for (int i = 0; i < 16; ++i)
#pragma unroll
      for (int r = 0; r < 4; ++r) o[i][r] *= scal[r];

    asm volatile("s_waitcnt lgkmcnt(0)" ::: "memory");  // cross-lane P visibility

    // ---- PV: A = P from LDS, B = V^T from global (L2-resident)
    __builtin_amdgcn_s_setprio(1);
#pragma unroll
    for (int kvc = 0; kvc < 2; ++kvc) {
      bf16x8 pa = *reinterpret_cast<const bf16x8*>(&P[wid][l15][kvc * 32 + lg * 8]);
      const unsigned short* vrow = vbase + kvb + kvc * 32;
#pragma unroll
      for (int dt = 0; dt < 16; ++dt) {
        bf16x8 vf = *reinterpret_cast<const bf16x8*>(vrow + (size_t)dt * 16 * SEQ);
        o[dt] = __builtin_amdgcn_mfma_f32_16x16x32_bf16(pa, vf, o[dt], 0, 0, 0);
      }
    }
    __builtin_amdgcn_s_setprio(0);

    __syncthreads();                                 // drain stage + LDS reuse
    cur ^= 1;
  }

#pragma unroll
  for (int dt = 0; dt < 16; ++dt)
#pragma unroll
    for (int r = 0; r < 4; ++r) {
      float v = o[dt][r] / lrow[r];
      attn[(size_t)(qb + lg * 4 + r) * HID + h * 256 + dt * 16 + l15] = f2bf(v);
    }
}

// ---------------------------------------------------------------- launcher
extern "C" void kernel_launch(void* const* d_in, const int* in_sizes, int n_in,
                              void* d_out, int out_size, void* d_ws, size_t ws_size,
                              hipStream_t stream) {
  const float* hs   = (const float*)d_in[0];
  const float* cosb = (const float*)d_in[1];
  const float* sinb = (const float*)d_in[2];
  const float* qkvw = (const float*)d_in[3];
  const float* ow   = (const float*)d_in[4];

  char* ws = (char*)d_ws;
  unsigned short* hs_bf   = (unsigned short*)(ws + 0);           // 16 MB
  unsigned short* wqkv_bf = (unsigned short*)(ws + 16777216);    // 12 MB
  unsigned short* wo_bf   = (unsigned short*)(ws + 29360128);    //  8 MB
  unsigned short* qkv_bf  = (unsigned short*)(ws + 37748736);    // 24 MB
  unsigned short* attn_bf = qkv_bf;                              // reuse (dead after postproc)
  unsigned short* q_bf    = (unsigned short*)(ws + 62914560);    // 16 MB
  unsigned short* k_bf    = (unsigned short*)(ws + 79691776);    //  4 MB
  unsigned short* vt_bf   = (unsigned short*)(ws + 83886080);    //  4 MB

  cvt_bf16<<<dim3((SEQ * HID / 4 + 255) / 256), dim3(256), 0, stream>>>(hs, hs_bf, SEQ * HID / 4);
  cvt_bf16<<<dim3((QKVN * HID / 4 + 255) / 256), dim3(256), 0, stream>>>(qkvw, wqkv_bf, QKVN * HID / 4);
  cvt_bf16<<<dim3((HID * HID / 4 + 255) / 256), dim3(256), 0, stream>>>(ow, wo_bf, HID * HID / 4);

  gemm_bt<true><<<dim3(QKVN / 128, SEQ / 128), dim3(256), 0, stream>>>(
      hs_bf, wqkv_bf, qkv_bf, SEQ, QKVN, HID);

  postproc<<<dim3(SEQ * 12 / 4), dim3(256), 0, stream>>>(qkv_bf, cosb, sinb, q_bf, k_bf, vt_bf);

  flash<<<dim3(512), dim3(256), 0, stream>>>(q_bf, k_bf, vt_bf, attn_bf);

  gemm_bt<false><<<dim3(HID / 128, SEQ / 128), dim3(256), 0, stream>>>(
      attn_bf, wo_bf, d_out, SEQ, HID, HID);
}

// Round 4
// 748.921 us; speedup vs baseline: 1.7822x; 1.1461x over previous
//
#include <hip/hip_runtime.h>

// Problem constants (fixed by the reference)
#define NHEADS 8
#define NKVH   2
#define HD     256
#define SEQ    4096
#define HID    2048
#define QKVN   3072   // (NH + 2*NKV) * D
#define SCAL   (1.0f/256.0f)

typedef __attribute__((ext_vector_type(8))) __bf16 bf16x8;
typedef __attribute__((ext_vector_type(4))) float  f32x4;

__device__ __forceinline__ unsigned short f2bf(float f) {
  unsigned int u = __builtin_bit_cast(unsigned int, f);
  u += 0x7fffu + ((u >> 16) & 1u);          // round-to-nearest-even
  return (unsigned short)(u >> 16);
}
__device__ __forceinline__ float bf2f(unsigned short b) {
  return __builtin_bit_cast(float, (unsigned int)b << 16);
}

// async global->LDS, 16B per lane (linear LDS dest = wave base + lane*16)
__device__ __forceinline__ void async_copy16(const void* g, void* l) {
  __builtin_amdgcn_global_load_lds(
      (__attribute__((address_space(1))) void*)(g),
      (__attribute__((address_space(3))) void*)(l), 16, 0, 0);
}

// ---------------------------------------------------------------- fp32->bf16
__global__ __launch_bounds__(256) void cvt_bf16(const float* __restrict__ in,
                                                unsigned short* __restrict__ out,
                                                int n4) {
  int i = blockIdx.x * 256 + threadIdx.x;
  if (i >= n4) return;
  float4 v = reinterpret_cast<const float4*>(in)[i];
  ushort4 o;
  o.x = f2bf(v.x); o.y = f2bf(v.y); o.z = f2bf(v.z); o.w = f2bf(v.w);
  reinterpret_cast<ushort4*>(out)[i] = o;
}

// ------------------------------------------------------- C = A(M,K) * B(N,K)^T
// 128x128 tile, BK=64, 4 waves as 2x2 of 64x64.  (verified rounds 1-2)
template <bool OUT_BF16>
__global__ __launch_bounds__(256) void gemm_bt(const unsigned short* __restrict__ A,
                                               const unsigned short* __restrict__ B,
                                               void* __restrict__ C,
                                               int M, int N, int K) {
  __shared__ __align__(16) unsigned short Als[128 * 64];
  __shared__ __align__(16) unsigned short Bls[128 * 64];
  const int t    = threadIdx.x;
  const int lane = t & 63;
  const int wid  = t >> 6;
  const int wr = wid >> 1, wc = wid & 1;
  const int l15 = lane & 15, lg = lane >> 4;
  const int m0 = blockIdx.y * 128, n0 = blockIdx.x * 128;

  f32x4 acc[4][4] = {};

  for (int k0 = 0; k0 < K; k0 += 64) {
    __syncthreads();                                  // LDS reuse fence
#pragma unroll
    for (int i = 0; i < 4; ++i) {
      int c   = i * 256 + t;                          // 16B chunk index 0..1023
      int kc  = c >> 9;
      int row = (c >> 2) & 127;
      int j8  = (c & 3) ^ (row & 3);                  // inverse-swizzled source
      int gcol = k0 + kc * 32 + j8 * 8;
      async_copy16(A + (size_t)(m0 + row) * K + gcol, Als + c * 8);
      async_copy16(B + (size_t)(n0 + row) * K + gcol, Bls + c * 8);
    }
    __syncthreads();                                  // drains vmcnt before use
#pragma unroll
    for (int kc = 0; kc < 2; ++kc) {
      bf16x8 af[4], bfr[4];
#pragma unroll
      for (int m = 0; m < 4; ++m) {
        int row   = wr * 64 + m * 16 + l15;
        int chunk = kc * 512 + row * 4 + (lg ^ (row & 3));
        af[m] = *reinterpret_cast<const bf16x8*>(Als + chunk * 8);
      }
#pragma unroll
      for (int n = 0; n < 4; ++n) {
        int row   = wc * 64 + n * 16 + l15;
        int chunk = kc * 512 + row * 4 + (lg ^ (row & 3));
        bfr[n] = *reinterpret_cast<const bf16x8*>(Bls + chunk * 8);
      }
#pragma unroll
      for (int m = 0; m < 4; ++m)
#pragma unroll
        for (int n = 0; n < 4; ++n)
          acc[m][n] = __builtin_amdgcn_mfma_f32_16x16x32_bf16(af[m], bfr[n],
                                                              acc[m][n], 0, 0, 0);
    }
  }

#pragma unroll
  for (int m = 0; m < 4; ++m) {
#pragma unroll
    for (int n = 0; n < 4; ++n) {
      int col = n0 + wc * 64 + n * 16 + l15;
#pragma unroll
      for (int r = 0; r < 4; ++r) {
        int rowg = m0 + wr * 64 + m * 16 + lg * 4 + r;   // C/D: row=(l>>4)*4+r
        if constexpr (OUT_BF16)
          reinterpret_cast<unsigned short*>(C)[(size_t)rowg * N + col] =
              f2bf(acc[m][n][r]);
        else
          reinterpret_cast<float*>(C)[(size_t)rowg * N + col] = acc[m][n][r];
      }
    }
  }
}

// --------------------------------------------- RMSNorm + RoPE + layout split
__global__ __launch_bounds__(256) void postproc(const unsigned short* __restrict__ qkv,
                                                const float* __restrict__ cosb,
                                                const float* __restrict__ sinb,
                                                unsigned short* __restrict__ q,
                                                unsigned short* __restrict__ k,
                                                unsigned short* __restrict__ vt) {
  const int wid = threadIdx.x >> 6, lane = threadIdx.x & 63;
  const int task = blockIdx.x * 4 + wid;          // 0 .. SEQ*12-1
  const int s = task / 12, comp = task % 12;

  ushort4 raw = reinterpret_cast<const ushort4*>(qkv + (size_t)task * 256)[lane];
  float x0 = bf2f(raw.x), x1 = bf2f(raw.y), x2 = bf2f(raw.z), x3 = bf2f(raw.w);

  float ss = x0 * x0 + x1 * x1 + x2 * x2 + x3 * x3;
#pragma unroll
  for (int m = 1; m < 64; m <<= 1) ss += __shfl_xor(ss, m);
  float inv = rsqrtf(ss * (1.0f / 256.0f) + 1e-6f);
  x0 *= inv; x1 *= inv; x2 *= inv; x3 *= inv;

  if (comp < 10) {  // RoPE: lane d-range 4*lane..4*lane+3, partner ±128
    float4 c  = reinterpret_cast<const float4*>(cosb + (size_t)s * 256)[lane];
    float4 sn = reinterpret_cast<const float4*>(sinb + (size_t)s * 256)[lane];
    float p0 = __shfl_xor(x0, 32), p1 = __shfl_xor(x1, 32);
    float p2 = __shfl_xor(x2, 32), p3 = __shfl_xor(x3, 32);
    float sg = (lane < 32) ? -1.0f : 1.0f;       // rotate_half sign
    x0 = x0 * c.x + sg * p0 * sn.x;
    x1 = x1 * c.y + sg * p1 * sn.y;
    x2 = x2 * c.z + sg * p2 * sn.z;
    x3 = x3 * c.w + sg * p3 * sn.w;
  }

  if (comp < 8) {
    ushort4 o;
    o.x = f2bf(x0 * SCAL); o.y = f2bf(x1 * SCAL);
    o.z = f2bf(x2 * SCAL); o.w = f2bf(x3 * SCAL);
    reinterpret_cast<ushort4*>(q + ((size_t)s * NHEADS + comp) * 256)[lane] = o;
  } else if (comp < 10) {
    ushort4 o;
    o.x = f2bf(x0); o.y = f2bf(x1); o.z = f2bf(x2); o.w = f2bf(x3);
    reinterpret_cast<ushort4*>(k + ((size_t)(comp - 8) * SEQ + s) * 256)[lane] = o;
  } else {  // v -> V^T[kvh][d][s]
    size_t base = (size_t)(comp - 10) * 256 * SEQ + s;
    int d0 = lane * 4;
    vt[base + (size_t)(d0 + 0) * SEQ] = f2bf(x0);
    vt[base + (size_t)(d0 + 1) * SEQ] = f2bf(x1);
    vt[base + (size_t)(d0 + 2) * SEQ] = f2bf(x2);
    vt[base + (size_t)(d0 + 3) * SEQ] = f2bf(x3);
  }
}

// --------------------------------------------------- causal flash attention
// Swapped-operand flash, barrier-free, split-KV (<=2 chunks per q-row).
// 896 blocks: bid = idx*8 + h (h=bid&7 pins kvh to XCD).  idx 0..111:
//   idx  0..31 : qt=32+idx,   tiles [0,31],  partial c0 (32 iters)
//   idx 32..63 : qt=95-idx,   tiles [32,qt], partial c1 (masked)
//   idx 64..79 : qt=16+idx-64,tiles [0,15],  partial c0 (16 iters)
//   idx 80..95 : qt=111-idx,  tiles [16,qt], partial c1 (masked)
//   idx 96..111: qt=111-idx,  tiles [0,qt],  direct     (masked)
// Each wave owns 16 q-rows.  QK^T computed swapped (Sᵀ): 4 lanes (same l15)
// share a q-row, softmax in-register + 2 shuffles.  PV computed as Oᵀ=Vᵀ·Pᵀ.
__global__ __launch_bounds__(256, 3) void flash(const unsigned short* __restrict__ q,
                                                const unsigned short* __restrict__ k,
                                                const unsigned short* __restrict__ vt,
                                                unsigned short* __restrict__ attn,
                                                unsigned short* __restrict__ opart,
                                                float* __restrict__ ml) {
  __shared__ __align__(16) unsigned short P[4][16][72];   // per-wave, pad 8
  const int lane = threadIdx.x & 63, wid = threadIdx.x >> 6;
  const int l15 = lane & 15, lg = lane >> 4;

  const int bid = blockIdx.x;
  const int h = bid & 7, kvh = h >> 2;
  const int idx = bid >> 3;
  int qt, t0, t1, mode;                    // mode: 0 direct, 1 c0, 2 c1
  if (idx < 32)       { qt = 32 + idx;       t0 = 0;  t1 = 31; mode = 1; }
  else if (idx < 64)  { qt = 95 - idx;       t0 = 32; t1 = qt; mode = 2; }
  else if (idx < 80)  { qt = 16 + idx - 64;  t0 = 0;  t1 = 15; mode = 1; }
  else if (idx < 96)  { qt = 111 - idx;      t0 = 16; t1 = qt; mode = 2; }
  else                { qt = 111 - idx;      t0 = 0;  t1 = qt; mode = 0; }

  const int qb = qt * 64 + wid * 16;

  // Q fragments (used as second MFMA operand; row q = l15, k-chunk = lg)
  bf16x8 qf[8];
  {
    const unsigned short* qrow = q + ((size_t)(qb + l15) * NHEADS + h) * 256 + lg * 8;
#pragma unroll
    for (int kc = 0; kc < 8; ++kc)
      qf[kc] = *reinterpret_cast<const bf16x8*>(qrow + kc * 32);
  }

  f32x4 o[16];
#pragma unroll
  for (int i = 0; i < 16; ++i) o[i] = f32x4{0.f, 0.f, 0.f, 0.f};
  float m = -1e30f, l = 0.f;

  const unsigned short* kb = k + (size_t)kvh * SEQ * 256 + lg * 8;
  const unsigned short* vb = vt + (size_t)kvh * 256 * SEQ + (size_t)l15 * SEQ + lg * 8;

  for (int t = t0; t <= t1; ++t) {
    const int kvb = t * 64;

    // ---- Sᵀ[kv,q] = K·Qᵀ :  A = K rows (kv), B = Q rows (q)
    f32x4 s[4];
    __builtin_amdgcn_s_setprio(1);
#pragma unroll
    for (int n = 0; n < 4; ++n) {
      f32x4 a = f32x4{0.f, 0.f, 0.f, 0.f};
      const unsigned short* kr = kb + (size_t)(kvb + n * 16 + l15) * 256;
#pragma unroll
      for (int kc = 0; kc < 8; ++kc) {
        bf16x8 kf = *reinterpret_cast<const bf16x8*>(kr + kc * 32);
        a = __builtin_amdgcn_mfma_f32_16x16x32_bf16(kf, qf[kc], a, 0, 0, 0);
      }
      s[n] = a;
    }
    __builtin_amdgcn_s_setprio(0);

    // causal mask on the diagonal tile.  Wave q-range is ONLY 16 rows
    // (qb..qb+15) vs 64-wide kv tile: gate must be kvb+63 >= qb.
    // (round-3 bug: "kvb+63 > qb+15" skipped the wid=3 diagonal wave)
    if (kvb + 64 > qb + 1) {
#pragma unroll
      for (int n = 0; n < 4; ++n)
#pragma unroll
        for (int r = 0; r < 4; ++r)
          if (kvb + n * 16 + lg * 4 + r > qb + l15) s[n][r] = -1e30f;
    }

    // ---- online softmax, row q = l15 shared by 4 lanes (lg=0..3)
    float m0 = fmaxf(fmaxf(s[0][0], s[0][1]), fmaxf(s[0][2], s[0][3]));
    float m1 = fmaxf(fmaxf(s[1][0], s[1][1]), fmaxf(s[1][2], s[1][3]));
    float m2 = fmaxf(fmaxf(s[2][0], s[2][1]), fmaxf(s[2][2], s[2][3]));
    float m3 = fmaxf(fmaxf(s[3][0], s[3][1]), fmaxf(s[3][2], s[3][3]));
    float pm = fmaxf(fmaxf(m0, m1), fmaxf(m2, m3));
    pm = fmaxf(pm, __shfl_xor(pm, 16));
    pm = fmaxf(pm, __shfl_xor(pm, 32));

    if (__any(pm > m + 8.0f)) {            // defer-max: rescale only when needed
      float mnew = fmaxf(m, pm);
      float sc = __expf(m - mnew);
#pragma unroll
      for (int i = 0; i < 16; ++i)
#pragma unroll
        for (int r = 0; r < 4; ++r) o[i][r] *= sc;
      l *= sc;
      m = mnew;
    }

#pragma unroll
    for (int n = 0; n < 4; ++n)
#pragma unroll
      for (int r = 0; r < 4; ++r) s[n][r] = __expf(s[n][r] - m);

    float r0 = (s[0][0] + s[0][1]) + (s[0][2] + s[0][3]);
    float r1 = (s[1][0] + s[1][1]) + (s[1][2] + s[1][3]);
    float r2 = (s[2][0] + s[2][1]) + (s[2][2] + s[2][3]);
    float r3 = (s[3][0] + s[3][1]) + (s[3][2] + s[3][3]);
    float rs = (r0 + r1) + (r2 + r3);
    rs += __shfl_xor(rs, 16);
    rs += __shfl_xor(rs, 32);
    l += rs;

    // P[q=l15][kv] -> per-wave LDS (b64 runs: kv = n*16 + lg*4 + r)
#pragma unroll
    for (int n = 0; n < 4; ++n) {
      ushort4 w;
      w.x = f2bf(s[n][0]); w.y = f2bf(s[n][1]);
      w.z = f2bf(s[n][2]); w.w = f2bf(s[n][3]);
      *reinterpret_cast<ushort4*>(&P[wid][l15][n * 16 + lg * 4]) = w;
    }
    asm volatile("s_waitcnt lgkmcnt(0)" ::: "memory");
    __builtin_amdgcn_sched_barrier(0);

    // ---- Oᵀ[d,q] += Vᵀ·Pᵀ :  A = Vᵀ rows (d), B = P rows (q)
    __builtin_amdgcn_s_setprio(1);
#pragma unroll
    for (int kvc = 0; kvc < 2; ++kvc) {
      bf16x8 pb = *reinterpret_cast<const bf16x8*>(&P[wid][l15][kvc * 32 + lg * 8]);
      const unsigned short* vr = vb + kvb + kvc * 32;
#pragma unroll
      for (int dt = 0; dt < 16; ++dt) {
        bf16x8 vf = *reinterpret_cast<const bf16x8*>(vr + (size_t)dt * 16 * SEQ);
        o[dt] = __builtin_amdgcn_mfma_f32_16x16x32_bf16(vf, pb, o[dt], 0, 0, 0);
      }
    }
    __builtin_amdgcn_s_setprio(0);
  }

  // ---- epilogue: lane holds Oᵀ[d = dt*16+lg*4+r, q = qb+l15]
  if (mode == 0) {
    float inv = 1.0f / l;
#pragma unroll
    for (int dt = 0; dt < 16; ++dt) {
      ushort4 w;
      w.x = f2bf(o[dt][0] * inv); w.y = f2bf(o[dt][1] * inv);
      w.z = f2bf(o[dt][2] * inv); w.w = f2bf(o[dt][3] * inv);
      *reinterpret_cast<ushort4*>(
          attn + (size_t)(qb + l15) * HID + h * 256 + dt * 16 + lg * 4) = w;
    }
  } else {
    size_t pidx = (size_t)(mode - 1) * 24576 + (size_t)h * 3072 + (qb + l15 - 1024);
#pragma unroll
    for (int dt = 0; dt < 16; ++dt) {
      ushort4 w;
      w.x = f2bf(o[dt][0]); w.y = f2bf(o[dt][1]);
      w.z = f2bf(o[dt][2]); w.w = f2bf(o[dt][3]);
      *reinterpret_cast<ushort4*>(opart + pidx * 256 + dt * 16 + lg * 4) = w;
    }
    if (lg == 0) reinterpret_cast<float2*>(ml)[pidx] = float2{m, l};
  }
}

// ----------------------------------------------------- split-KV merge pass
// rows s >= 1024 have exactly 2 partials; one wave per (h, s).
__global__ __launch_bounds__(256) void merge(const unsigned short* __restrict__ opart,
                                             const float* __restrict__ ml,
                                             unsigned short* __restrict__ attn) {
  const int wid = threadIdx.x >> 6, lane = threadIdx.x & 63;
  const int task = blockIdx.x * 4 + wid;          // 0..24575 = h*3072 + (s-1024)
  const int h = task / 3072, sr = task % 3072;

  float2 ab0 = reinterpret_cast<const float2*>(ml)[task];
  float2 ab1 = reinterpret_cast<const float2*>(ml)[24576 + task];
  float M  = fmaxf(ab0.x, ab1.x);
  float w0 = __expf(ab0.x - M), w1 = __expf(ab1.x - M);
  float invL = 1.0f / (w0 * ab0.y + w1 * ab1.y);
  w0 *= invL; w1 *= invL;

  ushort4 a = reinterpret_cast<const ushort4*>(opart + (size_t)task * 256)[lane];
  ushort4 b = reinterpret_cast<const ushort4*>(opart + (size_t)(24576 + task) * 256)[lane];
  ushort4 o;
  o.x = f2bf(w0 * bf2f(a.x) + w1 * bf2f(b.x));
  o.y = f2bf(w0 * bf2f(a.y) + w1 * bf2f(b.y));
  o.z = f2bf(w0 * bf2f(a.z) + w1 * bf2f(b.z));
  o.w = f2bf(w0 * bf2f(a.w) + w1 * bf2f(b.w));
  reinterpret_cast<ushort4*>(attn + (size_t)(1024 + sr) * HID + h * 256)[lane] = o;
}

// ---------------------------------------------------------------- launcher
extern "C" void kernel_launch(void* const* d_in, const int* in_sizes, int n_in,
                              void* d_out, int out_size, void* d_ws, size_t ws_size,
                              hipStream_t stream) {
  const float* hs   = (const float*)d_in[0];
  const float* cosb = (const float*)d_in[1];
  const float* sinb = (const float*)d_in[2];
  const float* qkvw = (const float*)d_in[3];
  const float* ow   = (const float*)d_in[4];

  char* ws = (char*)d_ws;
  unsigned short* hs_bf   = (unsigned short*)(ws + 0);           // 16 MB
  unsigned short* wqkv_bf = (unsigned short*)(ws + 16777216);    // 12 MB
  unsigned short* wo_bf   = (unsigned short*)(ws + 29360128);    //  8 MB
  unsigned short* qkv_bf  = (unsigned short*)(ws + 37748736);    // 24 MB
  unsigned short* attn_bf = qkv_bf;                              // reuse (dead after postproc)
  unsigned short* q_bf    = (unsigned short*)(ws + 62914560);    // 16 MB
  unsigned short* k_bf    = (unsigned short*)(ws + 79691776);    //  4 MB
  unsigned short* vt_bf   = (unsigned short*)(ws + 83886080);    //  4 MB
  // flash partials overlay the dead hs_bf/wqkv_bf regions:
  unsigned short* opart   = (unsigned short*)(ws + 0);           // 2*24576*256*2B = 24 MB
  float*          mlbuf   = (float*)(ws + 26214400);             // 384 KB (within wqkv region)

  cvt_bf16<<<dim3((SEQ * HID / 4 + 255) / 256), dim3(256), 0, stream>>>(hs, hs_bf, SEQ * HID / 4);
  cvt_bf16<<<dim3((QKVN * HID / 4 + 255) / 256), dim3(256), 0, stream>>>(qkvw, wqkv_bf, QKVN * HID / 4);
  cvt_bf16<<<dim3((HID * HID / 4 + 255) / 256), dim3(256), 0, stream>>>(ow, wo_bf, HID * HID / 4);

  gemm_bt<true><<<dim3(QKVN / 128, SEQ / 128), dim3(256), 0, stream>>>(
      hs_bf, wqkv_bf, qkv_bf, SEQ, QKVN, HID);

  postproc<<<dim3(SEQ * 12 / 4), dim3(256), 0, stream>>>(qkv_bf, cosb, sinb, q_bf, k_bf, vt_bf);

  flash<<<dim3(896), dim3(256), 0, stream>>>(q_bf, k_bf, vt_bf, attn_bf, opart, mlbuf);

  merge<<<dim3(6144), dim3(256), 0, stream>>>(opart, mlbuf, attn_bf);

  gemm_bt<false><<<dim3(HID / 128, SEQ / 128), dim3(256), 0, stream>>>(
      attn_bf, wo_bf, d_out, SEQ, HID, HID);
}

// Round 5
// 386.309 us; speedup vs baseline: 3.4551x; 1.9387x over previous
//
#include <hip/hip_runtime.h>

// Problem constants (fixed by the reference)
#define NHEADS 8
#define NKVH   2
#define HD     256
#define SEQ    4096
#define HID    2048
#define QKVN   3072   // (NH + 2*NKV) * D
#define SCAL   (1.0f/256.0f)

typedef __attribute__((ext_vector_type(8))) __bf16 bf16x8;
typedef __attribute__((ext_vector_type(4))) float  f32x4;

__device__ __forceinline__ unsigned short f2bf(float f) {
  unsigned int u = __builtin_bit_cast(unsigned int, f);
  u += 0x7fffu + ((u >> 16) & 1u);          // round-to-nearest-even
  return (unsigned short)(u >> 16);
}
__device__ __forceinline__ float bf2f(unsigned short b) {
  return __builtin_bit_cast(float, (unsigned int)b << 16);
}

// async global->LDS, 16B per lane (linear LDS dest = wave base + lane*16)
__device__ __forceinline__ void async_copy16(const void* g, void* l) {
  __builtin_amdgcn_global_load_lds(
      (__attribute__((address_space(1))) void*)(g),
      (__attribute__((address_space(3))) void*)(l), 16, 0, 0);
}

// ---------------------------------------------------------------- fp32->bf16
__global__ __launch_bounds__(256) void cvt_bf16(const float* __restrict__ in,
                                                unsigned short* __restrict__ out,
                                                int n4) {
  int i = blockIdx.x * 256 + threadIdx.x;
  if (i >= n4) return;
  float4 v = reinterpret_cast<const float4*>(in)[i];
  ushort4 o;
  o.x = f2bf(v.x); o.y = f2bf(v.y); o.z = f2bf(v.z); o.w = f2bf(v.w);
  reinterpret_cast<ushort4*>(out)[i] = o;
}

// ------------------------------------------------------- C = A(M,K) * B(N,K)^T
// 128x128 tile, BK=64, 4 waves as 2x2 of 64x64.  (verified rounds 1-4)
template <bool OUT_BF16>
__global__ __launch_bounds__(256) void gemm_bt(const unsigned short* __restrict__ A,
                                               const unsigned short* __restrict__ B,
                                               void* __restrict__ C,
                                               int M, int N, int K) {
  __shared__ __align__(16) unsigned short Als[128 * 64];
  __shared__ __align__(16) unsigned short Bls[128 * 64];
  const int t    = threadIdx.x;
  const int lane = t & 63;
  const int wid  = t >> 6;
  const int wr = wid >> 1, wc = wid & 1;
  const int l15 = lane & 15, lg = lane >> 4;
  const int m0 = blockIdx.y * 128, n0 = blockIdx.x * 128;

  f32x4 acc[4][4] = {};

  for (int k0 = 0; k0 < K; k0 += 64) {
    __syncthreads();                                  // LDS reuse fence
#pragma unroll
    for (int i = 0; i < 4; ++i) {
      int c   = i * 256 + t;                          // 16B chunk index 0..1023
      int kc  = c >> 9;
      int row = (c >> 2) & 127;
      int j8  = (c & 3) ^ (row & 3);                  // inverse-swizzled source
      int gcol = k0 + kc * 32 + j8 * 8;
      async_copy16(A + (size_t)(m0 + row) * K + gcol, Als + c * 8);
      async_copy16(B + (size_t)(n0 + row) * K + gcol, Bls + c * 8);
    }
    __syncthreads();                                  // drains vmcnt before use
#pragma unroll
    for (int kc = 0; kc < 2; ++kc) {
      bf16x8 af[4], bfr[4];
#pragma unroll
      for (int m = 0; m < 4; ++m) {
        int row   = wr * 64 + m * 16 + l15;
        int chunk = kc * 512 + row * 4 + (lg ^ (row & 3));
        af[m] = *reinterpret_cast<const bf16x8*>(Als + chunk * 8);
      }
#pragma unroll
      for (int n = 0; n < 4; ++n) {
        int row   = wc * 64 + n * 16 + l15;
        int chunk = kc * 512 + row * 4 + (lg ^ (row & 3));
        bfr[n] = *reinterpret_cast<const bf16x8*>(Bls + chunk * 8);
      }
#pragma unroll
      for (int m = 0; m < 4; ++m)
#pragma unroll
        for (int n = 0; n < 4; ++n)
          acc[m][n] = __builtin_amdgcn_mfma_f32_16x16x32_bf16(af[m], bfr[n],
                                                              acc[m][n], 0, 0, 0);
    }
  }

#pragma unroll
  for (int m = 0; m < 4; ++m) {
#pragma unroll
    for (int n = 0; n < 4; ++n) {
      int col = n0 + wc * 64 + n * 16 + l15;
#pragma unroll
      for (int r = 0; r < 4; ++r) {
        int rowg = m0 + wr * 64 + m * 16 + lg * 4 + r;   // C/D: row=(l>>4)*4+r
        if constexpr (OUT_BF16)
          reinterpret_cast<unsigned short*>(C)[(size_t)rowg * N + col] =
              f2bf(acc[m][n][r]);
        else
          reinterpret_cast<float*>(C)[(size_t)rowg * N + col] = acc[m][n][r];
      }
    }
  }
}

// --------------------------------------------- RMSNorm + RoPE + layout split
__global__ __launch_bounds__(256) void postproc(const unsigned short* __restrict__ qkv,
                                                const float* __restrict__ cosb,
                                                const float* __restrict__ sinb,
                                                unsigned short* __restrict__ q,
                                                unsigned short* __restrict__ k,
                                                unsigned short* __restrict__ vt) {
  const int wid = threadIdx.x >> 6, lane = threadIdx.x & 63;
  const int task = blockIdx.x * 4 + wid;          // 0 .. SEQ*12-1
  const int s = task / 12, comp = task % 12;

  ushort4 raw = reinterpret_cast<const ushort4*>(qkv + (size_t)task * 256)[lane];
  float x0 = bf2f(raw.x), x1 = bf2f(raw.y), x2 = bf2f(raw.z), x3 = bf2f(raw.w);

  float ss = x0 * x0 + x1 * x1 + x2 * x2 + x3 * x3;
#pragma unroll
  for (int m = 1; m < 64; m <<= 1) ss += __shfl_xor(ss, m);
  float inv = rsqrtf(ss * (1.0f / 256.0f) + 1e-6f);
  x0 *= inv; x1 *= inv; x2 *= inv; x3 *= inv;

  if (comp < 10) {  // RoPE: lane d-range 4*lane..4*lane+3, partner ±128
    float4 c  = reinterpret_cast<const float4*>(cosb + (size_t)s * 256)[lane];
    float4 sn = reinterpret_cast<const float4*>(sinb + (size_t)s * 256)[lane];
    float p0 = __shfl_xor(x0, 32), p1 = __shfl_xor(x1, 32);
    float p2 = __shfl_xor(x2, 32), p3 = __shfl_xor(x3, 32);
    float sg = (lane < 32) ? -1.0f : 1.0f;       // rotate_half sign
    x0 = x0 * c.x + sg * p0 * sn.x;
    x1 = x1 * c.y + sg * p1 * sn.y;
    x2 = x2 * c.z + sg * p2 * sn.z;
    x3 = x3 * c.w + sg * p3 * sn.w;
  }

  if (comp < 8) {
    ushort4 o;
    o.x = f2bf(x0 * SCAL); o.y = f2bf(x1 * SCAL);
    o.z = f2bf(x2 * SCAL); o.w = f2bf(x3 * SCAL);
    reinterpret_cast<ushort4*>(q + ((size_t)s * NHEADS + comp) * 256)[lane] = o;
  } else if (comp < 10) {
    ushort4 o;
    o.x = f2bf(x0); o.y = f2bf(x1); o.z = f2bf(x2); o.w = f2bf(x3);
    reinterpret_cast<ushort4*>(k + ((size_t)(comp - 8) * SEQ + s) * 256)[lane] = o;
  } else {  // v -> V^T[kvh][d][s]
    size_t base = (size_t)(comp - 10) * 256 * SEQ + s;
    int d0 = lane * 4;
    vt[base + (size_t)(d0 + 0) * SEQ] = f2bf(x0);
    vt[base + (size_t)(d0 + 1) * SEQ] = f2bf(x1);
    vt[base + (size_t)(d0 + 2) * SEQ] = f2bf(x2);
    vt[base + (size_t)(d0 + 3) * SEQ] = f2bf(x3);
  }
}

// --------------------------------------------------- causal flash attention
// v3: K AND V staged in LDS (double-buffered, global_load_lds w=16), shared
// by 8 waves; NO global loads in the compute body, so the end-of-iter
// __syncthreads vmcnt(0) drain only waits on the prefetch issued a full
// tile-compute earlier (T3 2-phase).  512 blocks: bid=(idx<<3)|h;
// idx<32: q-block b=idx, kv chunk c0=[0,2b+1]; idx>=32: b=63-idx,
// c1=[2b+2,4b+3].  Co-resident pairs (bid, bid+256) sum to 66 iters.
// Each wave: 16 q-rows; swapped QK^T (lane-local softmax); PV as O^T=V^T P^T.
// c0 writes unnormalized O to attn's final slot, c1 to opart; merge combines.
__global__ __launch_bounds__(512, 4) void flash(const unsigned short* __restrict__ q,
                                                const unsigned short* __restrict__ k,
                                                const unsigned short* __restrict__ vt,
                                                unsigned short* __restrict__ attn,
                                                unsigned short* __restrict__ opart,
                                                float* __restrict__ ml) {
  extern __shared__ __align__(16) unsigned short lds[];
  unsigned short* Kls = lds;            // [2][32*256]  2 x 16 KB, XOR-swizzled
  unsigned short* Vls = lds + 16384;    // [2][256*32]  2 x 16 KB
  unsigned short* Pls = lds + 32768;    // [8][16][40]  10 KB

  const int tid  = threadIdx.x;
  const int lane = tid & 63, wid = tid >> 6;
  const int l15 = lane & 15, lg = lane >> 4;

  const int bid = blockIdx.x;
  const int h = bid & 7, kvh = h >> 2;
  const int idx = bid >> 3;
  const int b  = (idx < 32) ? idx : 63 - idx;
  const int c  = (idx < 32) ? 0 : 1;
  const int t0 = c ? (2 * b + 2) : 0;
  const int t1 = c ? (4 * b + 3) : (2 * b + 1);
  const int qb = b * 128 + wid * 16;

  const unsigned short* kbase = k  + (size_t)kvh * SEQ * 256;
  const unsigned short* vtb   = vt + (size_t)kvh * 256 * SEQ;

  // Q fragments (B-operand of swapped QK: lane l15 = q-row, lg = k-chunk)
  bf16x8 qf[8];
  {
    const unsigned short* qrow = q + ((size_t)(qb + l15) * NHEADS + h) * 256 + lg * 8;
#pragma unroll
    for (int kc = 0; kc < 8; ++kc)
      qf[kc] = *reinterpret_cast<const bf16x8*>(qrow + kc * 32);
  }

  f32x4 o[16];
#pragma unroll
  for (int i = 0; i < 16; ++i) o[i] = f32x4{0.f, 0.f, 0.f, 0.f};
  float m = -1e30f, l = 0.f;

  // stage K (swizzled) + V (linear) tiles for kv range [t*32, t*32+31]
  auto stage = [&](int bb, int t) {
    const int kvb = t * 32;
#pragma unroll
    for (int i = 0; i < 2; ++i) {                  // K: 1024 chunks of 16B
      int p = i * 512 + tid;
      int krow = p >> 5, pj = p & 31;
      int j = (pj & ~7) | ((pj ^ krow) & 7);       // involution source swizzle
      async_copy16(kbase + (size_t)(kvb + krow) * 256 + j * 8,
                   Kls + bb * 8192 + p * 8);
    }
#pragma unroll
    for (int i = 0; i < 2; ++i) {                  // V^T: rows=d, 4 chunks/row
      int p = i * 512 + tid;
      int vrow = p >> 2, jc = p & 3;
      async_copy16(vtb + (size_t)vrow * SEQ + kvb + jc * 8,
                   Vls + bb * 8192 + p * 8);
    }
  };

  int cur = 0;
  stage(0, t0);
  __syncthreads();                                 // drains vmcnt(0)

  for (int t = t0; t <= t1; ++t) {
    const int kvb = t * 32;
    if (t + 1 <= t1) stage(cur ^ 1, t + 1);        // async prefetch next tile

    if (kvb <= qb + 15) {                          // skip fully-masked waves
      const unsigned short* Kc = Kls + cur * 8192;
      const unsigned short* Vc = Vls + cur * 8192;

      // ---- S^T[kv,q] = K.Q^T : A = K rows (kv), B = Q rows (q)
      f32x4 s[2];
      __builtin_amdgcn_s_setprio(1);
#pragma unroll
      for (int n = 0; n < 2; ++n) {
        f32x4 a = f32x4{0.f, 0.f, 0.f, 0.f};
        const int row = n * 16 + l15;
#pragma unroll
        for (int kc = 0; kc < 8; ++kc) {
          int j  = kc * 4 + lg;
          int pj = (j & ~7) | ((j ^ row) & 7);
          bf16x8 kf = *reinterpret_cast<const bf16x8*>(Kc + (row * 32 + pj) * 8);
          a = __builtin_amdgcn_mfma_f32_16x16x32_bf16(kf, qf[kc], a, 0, 0, 0);
        }
        s[n] = a;
      }
      __builtin_amdgcn_s_setprio(0);

      // causal mask: element (kv,q) masked if kv > q; gate if any kv > min q
      if (kvb + 31 > qb) {
#pragma unroll
        for (int n = 0; n < 2; ++n)
#pragma unroll
          for (int r = 0; r < 4; ++r)
            if (kvb + n * 16 + lg * 4 + r > qb + l15) s[n][r] = -1e30f;
      }

      // ---- online softmax, row q = l15 shared by 4 lanes (lg=0..3)
      float m0 = fmaxf(fmaxf(s[0][0], s[0][1]), fmaxf(s[0][2], s[0][3]));
      float m1 = fmaxf(fmaxf(s[1][0], s[1][1]), fmaxf(s[1][2], s[1][3]));
      float pm = fmaxf(m0, m1);
      pm = fmaxf(pm, __shfl_xor(pm, 16));
      pm = fmaxf(pm, __shfl_xor(pm, 32));

      if (__any(pm > m + 8.0f)) {          // defer-max rescale (THR=8)
        float mnew = fmaxf(m, pm);
        float sc = __expf(m - mnew);
#pragma unroll
        for (int i = 0; i < 16; ++i)
#pragma unroll
          for (int r = 0; r < 4; ++r) o[i][r] *= sc;
        l *= sc;
        m = mnew;
      }

#pragma unroll
      for (int n = 0; n < 2; ++n)
#pragma unroll
        for (int r = 0; r < 4; ++r) s[n][r] = __expf(s[n][r] - m);

      float rs = ((s[0][0] + s[0][1]) + (s[0][2] + s[0][3])) +
                 ((s[1][0] + s[1][1]) + (s[1][2] + s[1][3]));
      rs += __shfl_xor(rs, 16);
      rs += __shfl_xor(rs, 32);
      l += rs;

      // P[q=l15][kv] -> per-wave LDS (kv = n*16 + lg*4 + r), row pad to 40
      unsigned short* Pr = Pls + (wid * 16 + l15) * 40;
#pragma unroll
      for (int n = 0; n < 2; ++n) {
        ushort4 w;
        w.x = f2bf(s[n][0]); w.y = f2bf(s[n][1]);
        w.z = f2bf(s[n][2]); w.w = f2bf(s[n][3]);
        *reinterpret_cast<ushort4*>(Pr + n * 16 + lg * 4) = w;
      }
      asm volatile("s_waitcnt lgkmcnt(0)" ::: "memory");
      __builtin_amdgcn_sched_barrier(0);

      // ---- O^T[d,q] += V^T.P^T : A = V^T rows (d), B = P rows (q), k=32
      bf16x8 pb = *reinterpret_cast<const bf16x8*>(Pr + lg * 8);
      __builtin_amdgcn_s_setprio(1);
#pragma unroll
      for (int dt = 0; dt < 16; ++dt) {
        bf16x8 vf = *reinterpret_cast<const bf16x8*>(
            Vc + ((dt * 16 + l15) * 4 + lg) * 8);
        o[dt] = __builtin_amdgcn_mfma_f32_16x16x32_bf16(vf, pb, o[dt], 0, 0, 0);
      }
      __builtin_amdgcn_s_setprio(0);
    }

    __syncthreads();                               // drain prefetch + LDS reuse
    cur ^= 1;
  }

  // ---- epilogue: lane holds O^T[d = dt*16+lg*4+r, q = qb+l15], UNNORMALIZED
  const int rid = h * SEQ + qb + l15;
  if (c == 0) {
#pragma unroll
    for (int dt = 0; dt < 16; ++dt) {
      ushort4 w;
      w.x = f2bf(o[dt][0]); w.y = f2bf(o[dt][1]);
      w.z = f2bf(o[dt][2]); w.w = f2bf(o[dt][3]);
      *reinterpret_cast<ushort4*>(
          attn + (size_t)(qb + l15) * HID + h * 256 + dt * 16 + lg * 4) = w;
    }
    if (lg == 0) reinterpret_cast<float2*>(ml)[rid] = float2{m, l};
  } else {
#pragma unroll
    for (int dt = 0; dt < 16; ++dt) {
      ushort4 w;
      w.x = f2bf(o[dt][0]); w.y = f2bf(o[dt][1]);
      w.z = f2bf(o[dt][2]); w.w = f2bf(o[dt][3]);
      *reinterpret_cast<ushort4*>(opart + (size_t)rid * 256 + dt * 16 + lg * 4) = w;
    }
    if (lg == 0) reinterpret_cast<float2*>(ml)[32768 + rid] = float2{m, l};
  }
}

// ----------------------------------------------------- split-KV merge pass
// every q-row has exactly 2 partials: c0 (in attn, unnormalized) + c1 (opart).
__global__ __launch_bounds__(256) void merge(const unsigned short* __restrict__ opart,
                                             const float* __restrict__ ml,
                                             unsigned short* __restrict__ attn) {
  const int wid = threadIdx.x >> 6, lane = threadIdx.x & 63;
  const int rid = blockIdx.x * 4 + wid;           // 0..32767 = h*4096 + s
  const int h = rid >> 12, s = rid & 4095;

  float2 ab0 = reinterpret_cast<const float2*>(ml)[rid];
  float2 ab1 = reinterpret_cast<const float2*>(ml)[32768 + rid];
  float M  = fmaxf(ab0.x, ab1.x);
  float w0 = __expf(ab0.x - M), w1 = __expf(ab1.x - M);
  float invL = 1.0f / (w0 * ab0.y + w1 * ab1.y);
  w0 *= invL; w1 *= invL;

  unsigned short* arow = attn + (size_t)s * HID + h * 256;
  ushort4 a = reinterpret_cast<const ushort4*>(arow)[lane];
  ushort4 bq = reinterpret_cast<const ushort4*>(opart + (size_t)rid * 256)[lane];
  ushort4 o;
  o.x = f2bf(w0 * bf2f(a.x) + w1 * bf2f(bq.x));
  o.y = f2bf(w0 * bf2f(a.y) + w1 * bf2f(bq.y));
  o.z = f2bf(w0 * bf2f(a.z) + w1 * bf2f(bq.z));
  o.w = f2bf(w0 * bf2f(a.w) + w1 * bf2f(bq.w));
  reinterpret_cast<ushort4*>(arow)[lane] = o;
}

// ---------------------------------------------------------------- launcher
extern "C" void kernel_launch(void* const* d_in, const int* in_sizes, int n_in,
                              void* d_out, int out_size, void* d_ws, size_t ws_size,
                              hipStream_t stream) {
  const float* hs   = (const float*)d_in[0];
  const float* cosb = (const float*)d_in[1];
  const float* sinb = (const float*)d_in[2];
  const float* qkvw = (const float*)d_in[3];
  const float* ow   = (const float*)d_in[4];

  char* ws = (char*)d_ws;
  unsigned short* hs_bf   = (unsigned short*)(ws + 0);           // 16 MB (dead after QKV GEMM)
  unsigned short* wqkv_bf = (unsigned short*)(ws + 16777216);    // 12 MB (dead after QKV GEMM)
  unsigned short* wo_bf   = (unsigned short*)(ws + 29360128);    //  8 MB (live till final GEMM)
  unsigned short* qkv_bf  = (unsigned short*)(ws + 37748736);    // 24 MB (dead after postproc)
  unsigned short* attn_bf = qkv_bf;                              // 16 MB overlay
  unsigned short* q_bf    = (unsigned short*)(ws + 62914560);    // 16 MB
  unsigned short* k_bf    = (unsigned short*)(ws + 79691776);    //  4 MB
  unsigned short* vt_bf   = (unsigned short*)(ws + 83886080);    //  4 MB
  // flash partial overlays (regions dead after the QKV GEMM):
  unsigned short* opart   = (unsigned short*)(ws + 0);           // 16 MB (c1 partials)
  float*          mlbuf   = (float*)(ws + 26214400);             // 512 KB (2x32768 float2)

  cvt_bf16<<<dim3((SEQ * HID / 4 + 255) / 256), dim3(256), 0, stream>>>(hs, hs_bf, SEQ * HID / 4);
  cvt_bf16<<<dim3((QKVN * HID / 4 + 255) / 256), dim3(256), 0, stream>>>(qkvw, wqkv_bf, QKVN * HID / 4);
  cvt_bf16<<<dim3((HID * HID / 4 + 255) / 256), dim3(256), 0, stream>>>(ow, wo_bf, HID * HID / 4);

  gemm_bt<true><<<dim3(QKVN / 128, SEQ / 128), dim3(256), 0, stream>>>(
      hs_bf, wqkv_bf, qkv_bf, SEQ, QKVN, HID);

  postproc<<<dim3(SEQ * 12 / 4), dim3(256), 0, stream>>>(qkv_bf, cosb, sinb, q_bf, k_bf, vt_bf);

  flash<<<dim3(512), dim3(512), 75776, stream>>>(q_bf, k_bf, vt_bf, attn_bf, opart, mlbuf);

  merge<<<dim3(8192), dim3(256), 0, stream>>>(opart, mlbuf, attn_bf);

  gemm_bt<false><<<dim3(HID / 128, SEQ / 128), dim3(256), 0, stream>>>(
      attn_bf, wo_bf, d_out, SEQ, HID, HID);
}